// Round 2
// baseline (56.679 us; speedup 1.0000x reference)
//
#include <hip/hip_runtime.h>
#include <hip/hip_bf16.h>

// InteractionLayer: out[b, p] = dot(emb[b,i,:], emb[b,j,:]) for (i,j) in
// strict upper triangle of F=27, pair order = np.triu_indices(27, k=1).
// B=16384, F=27, D=128, f32 in / f32 out. Memory-bound (~250 MB @ ~6.3 TB/s).

#define FDIM 27
#define DDIM 128
#define NPAIR 351           // 27*26/2
#define NF4_ROW 32          // 128 floats = 32 float4 per row
#define NF4_TILE 864        // 27 * 32 float4 to stage
#define NTILE 28            // upper-tri (incl diag) 4x4 tiles of 7x7 grid

template <int CTRL>
__device__ __forceinline__ float dpp_add(float x) {
    // x + dpp_move(x, CTRL); pure VALU cross-lane (no DS pipe).
    int moved = __builtin_amdgcn_update_dpp(0, __float_as_int(x), CTRL, 0xF, 0xF, true);
    return x + __int_as_float(moved);
}

__global__ void InteractionLayer_35416300323238_kernel(
        const float* __restrict__ emb, float* __restrict__ out) {
    __shared__ float4 lds4[28 * NF4_ROW];   // 28 rows x 128 floats, linear
    __shared__ float res[NPAIR + 1];

    const int b = blockIdx.x;
    const int tid = threadIdx.x;

    // ---- stage 27x128 f32 tile into LDS, coalesced float4, linear layout ----
    const float4* __restrict__ src4 =
        reinterpret_cast<const float4*>(emb) + (size_t)b * NF4_TILE;
#pragma unroll
    for (int g = tid; g < NF4_TILE; g += 256) {
        lds4[g] = src4[g];
    }
    // zero-pad row 27 so 4x4 tiles need no bounds checks
    if (tid < NF4_ROW) {
        lds4[NF4_TILE + tid] = make_float4(0.f, 0.f, 0.f, 0.f);
    }
    __syncthreads();

    // ---- compute: tile = 4x4 block of the Gram matrix, 8 lanes share D ----
    const int tile = tid >> 3;   // 0..31, active if < 28
    const int c    = tid & 7;    // d-partition within tile
    if (tile < NTILE) {
        // map linear upper-tri tile index -> (ti, tj), tj >= ti, 7x7 grid
        int t = tile, ti = 0;
        while (t >= 7 - ti) { t -= 7 - ti; ++ti; }
        const int tj = ti + t;
        const int i0 = ti * 4, j0 = tj * 4;

        float acc[4][4] = {};
#pragma unroll
        for (int k = 0; k < 4; ++k) {
            // interleaved d-partition: float4 col index c + 8k
            // -> lane (tile,c) reads banks 4c..4c+3: all 32 banks covered
            const int col = c + (k << 3);
            float4 a0 = lds4[(i0 + 0) * NF4_ROW + col];
            float4 a1 = lds4[(i0 + 1) * NF4_ROW + col];
            float4 a2 = lds4[(i0 + 2) * NF4_ROW + col];
            float4 a3 = lds4[(i0 + 3) * NF4_ROW + col];
#pragma unroll
            for (int q = 0; q < 4; ++q) {
                const float4 bq = lds4[(j0 + q) * NF4_ROW + col];
                acc[0][q] = fmaf(a0.x, bq.x, fmaf(a0.y, bq.y, fmaf(a0.z, bq.z, fmaf(a0.w, bq.w, acc[0][q]))));
                acc[1][q] = fmaf(a1.x, bq.x, fmaf(a1.y, bq.y, fmaf(a1.z, bq.z, fmaf(a1.w, bq.w, acc[1][q]))));
                acc[2][q] = fmaf(a2.x, bq.x, fmaf(a2.y, bq.y, fmaf(a2.z, bq.z, fmaf(a2.w, bq.w, acc[2][q]))));
                acc[3][q] = fmaf(a3.x, bq.x, fmaf(a3.y, bq.y, fmaf(a3.z, bq.z, fmaf(a3.w, bq.w, acc[3][q]))));
            }
        }

        // ---- reduce across the 8 d-lanes ----
        // xor1/xor2 via DPP quad_perm (exact semantics); xor4 via __shfl_xor
        // (round-0 bug: row_ror:4 pulls from lane i-4 -> other tile's group).
#pragma unroll
        for (int p = 0; p < 4; ++p) {
#pragma unroll
            for (int q = 0; q < 4; ++q) {
                float v = acc[p][q];
                v = dpp_add<0xB1>(v);        // quad_perm [1,0,3,2] : xor 1
                v = dpp_add<0x4E>(v);        // quad_perm [2,3,0,1] : xor 2
                v += __shfl_xor(v, 4);       // xor 4: cross-quad, exact
                acc[p][q] = v;               // now valid on every lane
            }
        }

        if (c == 0) {
#pragma unroll
            for (int p = 0; p < 4; ++p) {
                const int i = i0 + p;
#pragma unroll
                for (int q = 0; q < 4; ++q) {
                    const int j = j0 + q;
                    if (j > i && j < FDIM) {
                        // pair index for np.triu_indices(27, k=1)
                        res[i * (53 - i) / 2 + (j - i - 1)] = acc[p][q];
                    }
                }
            }
        }
    }
    __syncthreads();

    // ---- coalesced output: 351 floats per batch row ----
    float* __restrict__ outb = out + (size_t)b * NPAIR;
    for (int t = tid; t < NPAIR; t += 256) {
        outb[t] = res[t];
    }
}

extern "C" void kernel_launch(void* const* d_in, const int* in_sizes, int n_in,
                              void* d_out, int out_size, void* d_ws, size_t ws_size,
                              hipStream_t stream) {
    const float* emb = (const float*)d_in[0];
    float* out = (float*)d_out;
    const int B = in_sizes[0] / (FDIM * DDIM);
    hipLaunchKernelGGL(InteractionLayer_35416300323238_kernel,
                       dim3(B), dim3(256), 0, stream, emb, out);
}

// Round 3
// 40.242 us; speedup vs baseline: 1.4085x; 1.4085x over previous
//
#include <hip/hip_runtime.h>
#include <hip/hip_bf16.h>

// InteractionLayer: out[b, p] = dot(emb[b,i,:], emb[b,j,:]) for (i,j) in
// strict upper triangle of F=27, pair order = np.triu_indices(27, k=1).
// B=16384, F=27, D=128, f32 in / f32 out.
//
// Round-3 design: one WAVE per batch (no cross-wave sharing, no barriers).
//   stage:  global f32 -> reg -> bf16 (RTNE) -> LDS [32][128] bf16,
//           XOR-swizzled (byte ^= (row&7)<<4) so fragment reads are
//           conflict-free (linear layout would be 16-way: stride 256B).
//   mfma:   Gram via mfma_f32_16x16x32_bf16. A-frag and B-frag layouts are
//           IDENTICAL for E (both: lane holds row/col = l&15, k = (l>>4)*8+e),
//           so 8 ds_read_b128 (2 row-groups x 4 k-groups) serve all operands.
//           3 C-tiles (00, 01, 11) x 4 k-steps = 12 MFMAs.
//   store:  triu entries scattered straight to global; consecutive lanes are
//           consecutive j -> 16-float (64B) segments.
// Rows 27..31 are never staged: their garbage feeds only discarded C rows/cols
// (each C element is an independent dot over the fully-valid K=128).

#define FDIM 27
#define DDIM 128
#define NPAIR 351
#define NF4 864            // 27*32 float4 per batch

typedef __attribute__((ext_vector_type(8))) short short8;
typedef __attribute__((ext_vector_type(4))) float f32x4;

__device__ __forceinline__ unsigned pack_bf16(float a, float b) {
    // RTNE f32->bf16, packed low(a)|high(b)
    unsigned ua = __float_as_uint(a), ub = __float_as_uint(b);
    ua = (ua + 0x7FFFu + ((ua >> 16) & 1u)) >> 16;
    ub = (ub + 0x7FFFu + ((ub >> 16) & 1u)) >> 16;
    return ua | (ub << 16);
}

__global__ __launch_bounds__(256)
void InteractionLayer_35416300323238_kernel(
        const float* __restrict__ emb, float* __restrict__ out, int B) {
    __shared__ char lds[4][32 * 128 * 2];   // per-wave 32x128 bf16 tile (8KB)

    const int tid = threadIdx.x;
    const int w   = tid >> 6;
    const int l   = tid & 63;
    const int b   = blockIdx.x * 4 + w;
    if (b >= B) return;
    char* __restrict__ L = lds[w];

    // ---- stage: 864 float4, coalesced; convert to bf16; swizzled ds_write ----
    const float4* __restrict__ src =
        reinterpret_cast<const float4*>(emb) + (size_t)b * NF4;
#pragma unroll
    for (int t = 0; t < 14; ++t) {
        const int g = l + 64 * t;
        if (t < 13 || g < NF4) {
            const float4 v = src[g];
            const int row    = g >> 5;          // 32 float4 per row
            const int linear = g << 3;          // byte offset = row*256 + (g%32)*8
            const int swz    = linear ^ ((row & 7) << 4);
            uint2 p;
            p.x = pack_bf16(v.x, v.y);
            p.y = pack_bf16(v.z, v.w);
            *reinterpret_cast<uint2*>(L + swz) = p;
        }
    }

    // ---- fragments: 2 row-groups x 4 k-groups, one ds_read_b128 each ----
    short8 frag[2][4];
#pragma unroll
    for (int rg = 0; rg < 2; ++rg) {
#pragma unroll
        for (int kg = 0; kg < 4; ++kg) {
            const int row    = rg * 16 + (l & 15);
            const int linear = row * 256 + kg * 64 + ((l >> 4) << 4);
            const int swz    = linear ^ ((row & 7) << 4);
            frag[rg][kg] = *reinterpret_cast<const short8*>(L + swz);
        }
    }

    // ---- Gram via MFMA: C = E x E^T, upper-tri 16x16 tiles ----
    f32x4 c00 = {0.f, 0.f, 0.f, 0.f};
    f32x4 c01 = {0.f, 0.f, 0.f, 0.f};
    f32x4 c11 = {0.f, 0.f, 0.f, 0.f};
#pragma unroll
    for (int kg = 0; kg < 4; ++kg) {
        c00 = __builtin_amdgcn_mfma_f32_16x16x32_bf16(frag[0][kg], frag[0][kg], c00, 0, 0, 0);
        c01 = __builtin_amdgcn_mfma_f32_16x16x32_bf16(frag[0][kg], frag[1][kg], c01, 0, 0, 0);
        c11 = __builtin_amdgcn_mfma_f32_16x16x32_bf16(frag[1][kg], frag[1][kg], c11, 0, 0, 0);
    }

    // ---- scatter triu entries: C/D layout col = l&15, row = (l>>4)*4 + reg ----
    float* __restrict__ ob = out + (size_t)b * NPAIR;
    const int jlo   = l & 15;
    const int ibase = (l >> 4) << 2;
#pragma unroll
    for (int r = 0; r < 4; ++r) {
        const int i = ibase + r;
        // tile 00: i in [0,16), j in [0,16)
        if (jlo > i)
            ob[i * (53 - i) / 2 + jlo - i - 1] = c00[r];
        // tile 01: i in [0,16), j = 16 + jlo
        const int j1 = 16 + jlo;
        if (j1 < FDIM)
            ob[i * (53 - i) / 2 + j1 - i - 1] = c01[r];
        // tile 11: i2 = 16 + i, j = 16 + jlo
        const int i2 = 16 + i;
        if (j1 > i2 && j1 < FDIM)
            ob[i2 * (53 - i2) / 2 + j1 - i2 - 1] = c11[r];
    }
}

extern "C" void kernel_launch(void* const* d_in, const int* in_sizes, int n_in,
                              void* d_out, int out_size, void* d_ws, size_t ws_size,
                              hipStream_t stream) {
    const float* emb = (const float*)d_in[0];
    float* out = (float*)d_out;
    const int B = in_sizes[0] / (FDIM * DDIM);
    hipLaunchKernelGGL(InteractionLayer_35416300323238_kernel,
                       dim3((B + 3) / 4), dim3(256), 0, stream, emb, out, B);
}